// Round 3
// baseline (1250.607 us; speedup 1.0000x reference)
//
#include <hip/hip_runtime.h>
#include <stdint.h>

#define Tsz 512
#define Dsz 256
#define NCYC 517   // pipeline depth 6: V1(t) V2(t-1) l1(t-2) l2(t-3) gx(t-4) gru(t-5)

union UHp { uint32_t u; _Float16 s[2]; };
__device__ __forceinline__ uint32_t packh(float a, float b) {
    UHp x; x.s[0] = (_Float16)a; x.s[1] = (_Float16)b; return x.u;
}
__device__ __forceinline__ float dot2(uint32_t w, uint32_t a, float c) {
#if __has_builtin(__builtin_amdgcn_fdot2)
    typedef _Float16 h2 __attribute__((ext_vector_type(2)));
    union U { uint32_t u; h2 h; };
    U W, A; W.u = w; A.u = a;
    return __builtin_amdgcn_fdot2(W.h, A.h, c, false);
#else
    float d;
    asm("v_dot2_f32_f16 %0, %1, %2, %3" : "=v"(d) : "v"(w), "v"(a), "v"(c));
    return d;
#endif
}
__device__ __forceinline__ float fsig(float x)  { return 1.0f / (1.0f + __expf(-x)); }
__device__ __forceinline__ float ftanh(float x) { return 2.0f / (1.0f + __expf(-2.0f * x)) - 1.0f; }

// acc = acc + dot of 4 f16-pairs (one uint4 of activations, 4 packed weights)
#define D4(ACC, WP, V) \
    do { ACC = dot2((WP)[0], (V).x, ACC); ACC = dot2((WP)[1], (V).y, ACC); \
         ACC = dot2((WP)[2], (V).z, ACC); ACC = dot2((WP)[3], (V).w, ACC); } while (0)

// One block = 2 batch rows, 960 threads = 15 waves, 1 block per CU (grid 256).
// Waves: w0,w1 = V1 (x@van_wi, k-halves) + pixel prefetch; w2 = V2 (h0 recur+relu);
// w3,w12 = gx (h2@gru_wi, k-halves); w4-7 = l1 (k-quarters, all 256 cols);
// w8-11 = l2 (k-quarters); w13 = gru-z (+row0 a/update); w14 = gru-r (+row1).
// Phase P1: matmul partials -> LDS.  Phase P2: cross-k reduce + gate math.
__global__ __launch_bounds__(960, 4) void rnn_pipe2(
    const float* __restrict__ pix,
    const float* __restrict__ van_wi, const float* __restrict__ van_bi,
    const float* __restrict__ van_wh, const float* __restrict__ van_bh,
    const float* __restrict__ w1g, const float* __restrict__ b1g,
    const float* __restrict__ w2g, const float* __restrict__ b2g,
    const float* __restrict__ gwi, const float* __restrict__ gwh,
    const float* __restrict__ gb,
    const float* __restrict__ mw1, const float* __restrict__ mb1,
    const float* __restrict__ mw2, const float* __restrict__ mb2,
    const float* __restrict__ mw3, const float* __restrict__ mb3,
    const float* __restrict__ sf,
    float* __restrict__ out)
{
    const int tid  = threadIdx.x;
    const int wv   = tid >> 6;
    const int lane = tid & 63;
    const int r0   = 2 * blockIdx.x;

    __shared__ __align__(16) uint32_t xbu[2][2][128];   // x(t) f16 [buf][row][128 u32]
    __shared__ __align__(16) float    vp[2][2][2][32];  // van partials [buf][khalf][row][col]
    __shared__ __align__(16) uint32_t hcat1[2][2][48];  // [h0(32f16)|h1(64f16)] per row
    __shared__ __align__(16) uint32_t hcat2[2][2][64];  // [h1(64f16)|h2(64f16)] per row
    __shared__ __align__(16) float    g1p[4][2][256];   // l1 gate partials [kq][row][col]
    __shared__ __align__(16) float    g2p[4][2][256];
    __shared__ __align__(16) float    gxp[2][2][2][192];// gx partials [buf][kh][row][col]
    __shared__ __align__(16) float    zb[2][64];
    __shared__ __align__(16) uint32_t rhu[2][32];       // r*h3 f16 [row][32 u32]
    __shared__ __align__(16) uint32_t h3u[2][32];       // h3 f16
    __shared__ float sHf[2][64];
    __shared__ float sT[2][64];
    __shared__ float sP[2][12];

    uint32_t wreg[64];
    float bc0 = 0.f, bc1 = 0.f, bc2 = 0.f, bc3 = 0.f;
    float creg = 0.f;   // lstm cell state (l1/l2 update lanes)
    float h3f  = 0.f;   // gru hidden state f32 (w13 row0 / w14 row1)
    float4 pxA{}, pxB{};
    const float* pr = nullptr;

    // ---------------- per-role weight load ----------------
    if (wv <= 1) {                       // V1: x @ van_wi, k-half = wv
        const int col = lane & 31;
#pragma unroll
        for (int i = 0; i < 64; ++i)
            wreg[i] = packh(van_wi[(128 * wv + 2 * i) * 32 + col],
                            van_wi[(128 * wv + 2 * i + 1) * 32 + col]);
        pr = pix + (size_t)(r0 + wv) * Tsz * Dsz;
        float4 p0 = *(const float4*)(pr + 4 * lane);
        uint2 w; w.x = packh(p0.x, p0.y); w.y = packh(p0.z, p0.w);
        ((uint2*)xbu[1][wv])[lane] = w;
        pxA = *(const float4*)(pr + Dsz + 4 * lane);
        pxB = *(const float4*)(pr + 2 * (size_t)Dsz + 4 * lane);
    } else if (wv == 2) {                // V2: h0 @ van_wh
        const int col = lane & 31;
#pragma unroll
        for (int i = 0; i < 16; ++i)
            wreg[i] = packh(van_wh[(2 * i) * 32 + col], van_wh[(2 * i + 1) * 32 + col]);
        bc0 = van_bi[col] + van_bh[col];
    } else if (wv == 3 || wv == 12) {    // gx: h2 @ gru_wi, k-half
        const int kh = (wv == 3) ? 0 : 1;
#pragma unroll
        for (int c = 0; c < 3; ++c)
#pragma unroll
            for (int i = 0; i < 16; ++i)
                wreg[c * 16 + i] = packh(gwi[(32 * kh + 2 * i) * 192 + c * 64 + lane],
                                         gwi[(32 * kh + 2 * i + 1) * 192 + c * 64 + lane]);
        if (kh == 0) { bc0 = gb[lane]; bc1 = gb[64 + lane]; bc2 = gb[128 + lane]; }
    } else if (wv <= 7) {                // l1: k-quarter kh = wv-4
        const int kh = wv - 4;
#pragma unroll
        for (int c = 0; c < 4; ++c)
#pragma unroll
            for (int i = 0; i < 12; ++i)
                wreg[c * 12 + i] = packh(w1g[(24 * kh + 2 * i) * 256 + c * 64 + lane],
                                         w1g[(24 * kh + 2 * i + 1) * 256 + c * 64 + lane]);
        if (kh == 0) { bc0 = b1g[lane]; bc1 = b1g[64 + lane]; bc2 = b1g[128 + lane]; bc3 = b1g[192 + lane]; }
    } else if (wv <= 11) {               // l2: k-quarter kh = wv-8
        const int kh = wv - 8;
#pragma unroll
        for (int c = 0; c < 4; ++c)
#pragma unroll
            for (int i = 0; i < 16; ++i)
                wreg[c * 16 + i] = packh(w2g[(32 * kh + 2 * i) * 256 + c * 64 + lane],
                                         w2g[(32 * kh + 2 * i + 1) * 256 + c * 64 + lane]);
        if (kh == 0) { bc0 = b2g[lane]; bc1 = b2g[64 + lane]; bc2 = b2g[128 + lane]; bc3 = b2g[192 + lane]; }
    } else {                             // w13/w14: gru z/r + a
        const int rsel = wv - 13;
        const int zrcol = rsel * 64 + lane;
#pragma unroll
        for (int i = 0; i < 32; ++i) {
            wreg[i]      = packh(gwh[(2 * i) * 192 + zrcol], gwh[(2 * i + 1) * 192 + zrcol]);
            wreg[32 + i] = packh(gwh[(2 * i) * 192 + 128 + lane], gwh[(2 * i + 1) * 192 + 128 + lane]);
        }
    }

    if (tid < 192) ((uint32_t*)hcat1)[tid] = 0u;
    if (tid < 256) ((uint32_t*)hcat2)[tid] = 0u;
    if (tid < 64)  ((uint32_t*)h3u)[tid] = 0u;
    __syncthreads();

    // ---------------- pipelined recurrence ----------------
    for (int n = 0; n < NCYC; ++n) {
        const int wb = n & 1, rb = wb ^ 1;

        // ================= P1 =================
        if (wv <= 1) {
            if (n + 1 < Tsz) {
                uint2 w; w.x = packh(pxA.x, pxA.y); w.y = packh(pxA.z, pxA.w);
                ((uint2*)xbu[wb][wv])[lane] = w;
            }
            pxA = pxB;
            if (n + 3 < Tsz) pxB = *(const float4*)(pr + (size_t)(n + 3) * Dsz + 4 * lane);
            if (n < Tsz) {
                const int row = lane >> 5, col = lane & 31;
                const uint4* xq = ((const uint4*)xbu[rb][row]) + 16 * wv;
                float a0 = 0.f, a1 = 0.f, a2 = 0.f, a3 = 0.f;
#pragma unroll
                for (int q = 0; q < 16; q += 4) {
                    uint4 v0 = xq[q], v1 = xq[q + 1], v2 = xq[q + 2], v3 = xq[q + 3];
                    D4(a0, &wreg[4 * q + 0],  v0);
                    D4(a1, &wreg[4 * q + 4],  v1);
                    D4(a2, &wreg[4 * q + 8],  v2);
                    D4(a3, &wreg[4 * q + 12], v3);
                }
                vp[wb][wv][row][col] = (a0 + a1) + (a2 + a3);
            }
        } else if (wv == 2) {
            if (n >= 1 && n <= Tsz) {
                const int row = lane >> 5, col = lane & 31;
                const uint4* hq = (const uint4*)hcat1[rb][row];
                float a0 = 0.f, a1 = 0.f;
#pragma unroll
                for (int q = 0; q < 4; ++q) {
                    uint4 v = hq[q];
                    if (q & 1) { D4(a1, &wreg[4 * q], v); } else { D4(a0, &wreg[4 * q], v); }
                }
                float hv = vp[rb][0][row][col] + vp[rb][1][row][col] + bc0 + a0 + a1;
                ((_Float16*)hcat1[wb][row])[col] = (_Float16)fmaxf(hv, 0.f);
            }
        } else if (wv == 3 || wv == 12) {
            const int kh = (wv == 3) ? 0 : 1;
            if (n >= 4 && n - 4 < Tsz) {
                const uint4* q0 = ((const uint4*)hcat2[rb][0]) + 8 + 4 * kh;
                const uint4* q1 = ((const uint4*)hcat2[rb][1]) + 8 + 4 * kh;
                float ac[3][2];
                ac[0][0] = bc0; ac[0][1] = bc0; ac[1][0] = bc1; ac[1][1] = bc1;
                ac[2][0] = bc2; ac[2][1] = bc2;
#pragma unroll
                for (int q = 0; q < 4; ++q) {
                    uint4 v0 = q0[q], v1 = q1[q];
#pragma unroll
                    for (int c = 0; c < 3; ++c) {
                        D4(ac[c][0], &wreg[c * 16 + 4 * q], v0);
                        D4(ac[c][1], &wreg[c * 16 + 4 * q], v1);
                    }
                }
#pragma unroll
                for (int c = 0; c < 3; ++c) {
                    gxp[wb][kh][0][c * 64 + lane] = ac[c][0];
                    gxp[wb][kh][1][c * 64 + lane] = ac[c][1];
                }
            }
        } else if (wv <= 7) {
            const int kh = wv - 4;
            if (n >= 2 && n - 2 < Tsz) {
                const uint4* q0 = ((const uint4*)hcat1[rb][0]) + 3 * kh;
                const uint4* q1 = ((const uint4*)hcat1[rb][1]) + 3 * kh;
                float ac[4][2];
                ac[0][0] = bc0; ac[0][1] = bc0; ac[1][0] = bc1; ac[1][1] = bc1;
                ac[2][0] = bc2; ac[2][1] = bc2; ac[3][0] = bc3; ac[3][1] = bc3;
#pragma unroll
                for (int q = 0; q < 3; ++q) {
                    uint4 v0 = q0[q], v1 = q1[q];
#pragma unroll
                    for (int c = 0; c < 4; ++c) {
                        D4(ac[c][0], &wreg[c * 12 + 4 * q], v0);
                        D4(ac[c][1], &wreg[c * 12 + 4 * q], v1);
                    }
                }
#pragma unroll
                for (int c = 0; c < 4; ++c) {
                    g1p[kh][0][c * 64 + lane] = ac[c][0];
                    g1p[kh][1][c * 64 + lane] = ac[c][1];
                }
            }
        } else if (wv <= 11) {
            const int kh = wv - 8;
            if (n >= 3 && n - 3 < Tsz) {
                const uint4* q0 = ((const uint4*)hcat2[rb][0]) + 4 * kh;
                const uint4* q1 = ((const uint4*)hcat2[rb][1]) + 4 * kh;
                float ac[4][2];
                ac[0][0] = bc0; ac[0][1] = bc0; ac[1][0] = bc1; ac[1][1] = bc1;
                ac[2][0] = bc2; ac[2][1] = bc2; ac[3][0] = bc3; ac[3][1] = bc3;
#pragma unroll
                for (int q = 0; q < 4; ++q) {
                    uint4 v0 = q0[q], v1 = q1[q];
#pragma unroll
                    for (int c = 0; c < 4; ++c) {
                        D4(ac[c][0], &wreg[c * 16 + 4 * q], v0);
                        D4(ac[c][1], &wreg[c * 16 + 4 * q], v1);
                    }
                }
#pragma unroll
                for (int c = 0; c < 4; ++c) {
                    g2p[kh][0][c * 64 + lane] = ac[c][0];
                    g2p[kh][1][c * 64 + lane] = ac[c][1];
                }
            }
        } else {
            const int rsel = wv - 13;
            if (n >= 5 && n - 5 < Tsz) {
                const int zrcol = rsel * 64 + lane;
                const uint4* h3q0 = (const uint4*)h3u[0];
                const uint4* h3q1 = (const uint4*)h3u[1];
                float a0 = gxp[rb][0][0][zrcol] + gxp[rb][1][0][zrcol];
                float a1 = gxp[rb][0][1][zrcol] + gxp[rb][1][1][zrcol];
                float b0 = 0.f, b1v = 0.f;
#pragma unroll
                for (int q = 0; q < 8; ++q) {
                    uint4 v0 = h3q0[q], v1 = h3q1[q];
                    if (q & 1) { D4(b0, &wreg[4 * q], v0); D4(b1v, &wreg[4 * q], v1); }
                    else       { D4(a0, &wreg[4 * q], v0); D4(a1,  &wreg[4 * q], v1); }
                }
                float s0 = fsig(a0 + b0), s1 = fsig(a1 + b1v);
                if (rsel == 0) {
                    zb[0][lane] = s0; zb[1][lane] = s1;
                } else {
                    float h30 = (float)((const _Float16*)h3u[0])[lane];
                    float h31 = (float)((const _Float16*)h3u[1])[lane];
                    ((_Float16*)rhu[0])[lane] = (_Float16)(s0 * h30);
                    ((_Float16*)rhu[1])[lane] = (_Float16)(s1 * h31);
                }
            }
        }
        __syncthreads();

        // ================= P2 =================
        if (wv >= 4 && wv <= 7) {
            const int kh = wv - 4;
            if (n >= 2 && n - 2 < Tsz && lane < 32) {
                const int r = lane >> 4, u = 16 * kh + (lane & 15);
                float gi = 0.f, gg = 0.f, gf = 0.f, go = 0.f;
#pragma unroll
                for (int q = 0; q < 4; ++q) {
                    gi += g1p[q][r][u];       gg += g1p[q][r][64 + u];
                    gf += g1p[q][r][128 + u]; go += g1p[q][r][192 + u];
                }
                float cc = fsig(gf + 1.f) * creg + fsig(gi) * ftanh(gg);
                creg = cc;
                float hh = fsig(go) * ftanh(cc);
                ((_Float16*)hcat1[wb][r])[32 + u] = (_Float16)hh;
                ((_Float16*)hcat2[wb][r])[u]      = (_Float16)hh;
            }
        } else if (wv >= 8 && wv <= 11) {
            const int kh = wv - 8;
            if (n >= 3 && n - 3 < Tsz && lane < 32) {
                const int r = lane >> 4, u = 16 * kh + (lane & 15);
                float gi = 0.f, gg = 0.f, gf = 0.f, go = 0.f;
#pragma unroll
                for (int q = 0; q < 4; ++q) {
                    gi += g2p[q][r][u];       gg += g2p[q][r][64 + u];
                    gf += g2p[q][r][128 + u]; go += g2p[q][r][192 + u];
                }
                float cc = fsig(gf + 1.f) * creg + fsig(gi) * ftanh(gg);
                creg = cc;
                float hh = fsig(go) * ftanh(cc);
                ((_Float16*)hcat2[wb][r])[64 + u] = (_Float16)hh;
            }
        } else if (wv >= 13) {
            const int rsel = wv - 13;
            if (n >= 5 && n - 5 < Tsz) {
                float acc = gxp[rb][0][rsel][128 + lane] + gxp[rb][1][rsel][128 + lane];
                float ac2 = 0.f;
                const uint4* rq = (const uint4*)rhu[rsel];
#pragma unroll
                for (int q = 0; q < 8; ++q) {
                    uint4 v = rq[q];
                    if (q & 1) { D4(ac2, &wreg[32 + 4 * q], v); }
                    else       { D4(acc, &wreg[32 + 4 * q], v); }
                }
                float av = ftanh(acc + ac2);
                float z = zb[rsel][lane];
                h3f = (1.f - z) * h3f + z * av;
                ((_Float16*)h3u[rsel])[lane] = (_Float16)h3f;
            }
        }
        __syncthreads();
    }

    // ---------------- MLP head (2 rows) ----------------
    if (wv == 13) sHf[0][lane] = h3f;
    if (wv == 14) sHf[1][lane] = h3f;
    __syncthreads();
    if (tid < 64) {
        const int r = tid >> 5, c = tid & 31;
        float acc = mb1[c];
#pragma unroll
        for (int k = 0; k < 64; ++k) acc = fmaf(sHf[r][k], mw1[k * 32 + c], acc);
        sT[r][c] = fmaxf(acc, 0.f);
    }
    __syncthreads();
    if (tid < 64) {
        const int r = tid >> 5, c = tid & 31;
        float acc = mb2[c];
#pragma unroll
        for (int k = 0; k < 32; ++k) acc = fmaf(sT[r][k], mw2[k * 32 + c], acc);
        sT[r][32 + c] = fmaxf(acc, 0.f);
    }
    __syncthreads();
    if (tid < 24) {
        const int r = tid / 12, c = tid - 12 * r;
        float acc = mb3[c];
#pragma unroll
        for (int k = 0; k < 32; ++k) acc = fmaf(sT[r][32 + k], mw3[k * 12 + c], acc);
        sP[r][c] = acc;
    }
    __syncthreads();
    if (tid < 2) {
        float acc = 0.f;
#pragma unroll
        for (int k = 0; k < 12; ++k) acc = fmaf(sP[tid][k], sf[k], acc);
        out[24 + r0 + tid] = acc;
    }
    if (blockIdx.x == 0 && tid < 12) {
        out[tid] = sf[tid];
        out[12 + tid] = 1.0f;
    }
}

extern "C" void kernel_launch(void* const* d_in, const int* in_sizes, int n_in,
                              void* d_out, int out_size, void* d_ws, size_t ws_size,
                              hipStream_t stream) {
    (void)in_sizes; (void)n_in; (void)d_ws; (void)ws_size; (void)out_size;
    const float* pix    = (const float*)d_in[0];
    const float* van_wi = (const float*)d_in[1];
    const float* van_bi = (const float*)d_in[2];
    const float* van_wh = (const float*)d_in[3];
    const float* van_bh = (const float*)d_in[4];
    const float* w1     = (const float*)d_in[5];
    const float* b1     = (const float*)d_in[6];
    const float* w2     = (const float*)d_in[7];
    const float* b2     = (const float*)d_in[8];
    const float* gwi    = (const float*)d_in[9];
    const float* gwh    = (const float*)d_in[10];
    const float* gb     = (const float*)d_in[11];
    const float* mw1    = (const float*)d_in[12];
    const float* mb1    = (const float*)d_in[13];
    const float* mw2    = (const float*)d_in[14];
    const float* mb2    = (const float*)d_in[15];
    const float* mw3    = (const float*)d_in[16];
    const float* mb3    = (const float*)d_in[17];
    const float* sf     = (const float*)d_in[18];
    float* out = (float*)d_out;

    rnn_pipe2<<<256, 960, 0, stream>>>(
        pix, van_wi, van_bi, van_wh, van_bh,
        w1, b1, w2, b2, gwi, gwh, gb,
        mw1, mb1, mw2, mb2, mw3, mb3, sf, out);
}

// Round 4
// 860.896 us; speedup vs baseline: 1.4527x; 1.4527x over previous
//
#include <hip/hip_runtime.h>
#include <stdint.h>

#define Tsz 512
#define Dsz 256
#define NCYC (Tsz + 4)   // depth 5: van(t) l1(t-1) l2(t-2) gx(t-3) gru(t-4)

union UHp { uint32_t u; _Float16 s[2]; };
__device__ __forceinline__ uint32_t packh(float a, float b) {
    UHp x; x.s[0] = (_Float16)a; x.s[1] = (_Float16)b; return x.u;
}
__device__ __forceinline__ float dot2(uint32_t w, uint32_t a, float c) {
#if __has_builtin(__builtin_amdgcn_fdot2)
    typedef _Float16 h2 __attribute__((ext_vector_type(2)));
    union U { uint32_t u; h2 h; };
    U W, A; W.u = w; A.u = a;
    return __builtin_amdgcn_fdot2(W.h, A.h, c, false);
#else
    float d;
    asm("v_dot2_f32_f16 %0, %1, %2, %3" : "=v"(d) : "v"(w), "v"(a), "v"(c));
    return d;
#endif
}
__device__ __forceinline__ float fsig(float x)  { return 1.0f / (1.0f + __expf(-x)); }
__device__ __forceinline__ float ftanh(float x) { return 2.0f / (1.0f + __expf(-2.0f * x)) - 1.0f; }

// all 4 words -> one accumulator
#define D4(ACC, WP, V) \
    do { ACC = dot2((WP)[0], (V).x, ACC); ACC = dot2((WP)[1], (V).y, ACC); \
         ACC = dot2((WP)[2], (V).z, ACC); ACC = dot2((WP)[3], (V).w, ACC); } while (0)
// alternate words across two accumulators (breaks dependent chains)
#define D4X(A, X, WP, V) \
    do { A = dot2((WP)[0], (V).x, A); X = dot2((WP)[1], (V).y, X); \
         A = dot2((WP)[2], (V).z, A); X = dot2((WP)[3], (V).w, X); } while (0)

// Block = 2 batch rows, 448 threads = 7 waves, grid 256 (1 block/CU, one pass).
//  w0: van (both rows) + pixel prefetch
//  w1-2: lstm1 (128 lanes; lane pair = unit u; even: i,g  odd: f,o; shfl_xor(1))
//  w3-4: lstm2 (same scheme, k=128)
//  w5: gru gx = h2 @ gru_wi + b (both rows)
//  w6: gru recurrent z/r/a + h3 update (both rows, wave-synchronous)
__global__ __launch_bounds__(448, 2) void rnn_pipe3(
    const float* __restrict__ pix,
    const float* __restrict__ van_wi, const float* __restrict__ van_bi,
    const float* __restrict__ van_wh, const float* __restrict__ van_bh,
    const float* __restrict__ w1g, const float* __restrict__ b1g,
    const float* __restrict__ w2g, const float* __restrict__ b2g,
    const float* __restrict__ gwi, const float* __restrict__ gwh,
    const float* __restrict__ gb,
    const float* __restrict__ mw1, const float* __restrict__ mb1,
    const float* __restrict__ mw2, const float* __restrict__ mb2,
    const float* __restrict__ mw3, const float* __restrict__ mb3,
    const float* __restrict__ sf,
    float* __restrict__ out)
{
    const int tid  = threadIdx.x;
    const int wv   = tid >> 6;
    const int lane = tid & 63;
    const int r0   = 2 * blockIdx.x;

    __shared__ __align__(16) _Float16 xb [2][2][256];   // [buf][row][256]
    __shared__ __align__(16) _Float16 h0b[2][2][32];
    __shared__ __align__(16) _Float16 h1b[2][2][64];
    __shared__ __align__(16) _Float16 h2b[2][2][64];
    __shared__ __align__(16) _Float16 gxb[2][2][192];
    __shared__ __align__(16) _Float16 h3s[2][64];       // [row]
    __shared__ __align__(16) _Float16 rh3s[2][64];
    __shared__ float sHf[2][64];
    __shared__ float sT[2][64];
    __shared__ float sP[2][12];

    uint32_t wreg[128];
    float bz0 = 0.f, bz1 = 0.f, bz2 = 0.f;
    float st0 = 0.f, st1 = 0.f;          // per-role state: lstm c (rows 0/1) or gru h3
    float4 pxA0{}, pxB0{}, pxA1{}, pxB1{};
    const float* pr0 = nullptr; const float* pr1 = nullptr;

    // ---------------- per-role weight load (once) ----------------
    if (wv == 0) {                        // van: x@wi + h0@wh, 2-way k-split (s)
        const int c = lane & 31, s = lane >> 5;
#pragma unroll
        for (int j = 0; j < 64; ++j)
            wreg[j] = packh(van_wi[(128 * s + 2 * j) * 32 + c],
                            van_wi[(128 * s + 2 * j + 1) * 32 + c]);
#pragma unroll
        for (int j = 0; j < 8; ++j)
            wreg[64 + j] = packh(van_wh[(16 * s + 2 * j) * 32 + c],
                                 van_wh[(16 * s + 2 * j + 1) * 32 + c]);
        bz0 = van_bi[c] + van_bh[c];
        pr0 = pix + (size_t)r0 * Tsz * Dsz;
        pr1 = pr0 + (size_t)Tsz * Dsz;
        float4 p0 = *(const float4*)(pr0 + 4 * lane);
        float4 p1 = *(const float4*)(pr1 + 4 * lane);
        uint32_t* x0 = (uint32_t*)xb[1][0];
        uint32_t* x1 = (uint32_t*)xb[1][1];
        x0[2 * lane] = packh(p0.x, p0.y); x0[2 * lane + 1] = packh(p0.z, p0.w);
        x1[2 * lane] = packh(p1.x, p1.y); x1[2 * lane + 1] = packh(p1.z, p1.w);
        pxA0 = *(const float4*)(pr0 + Dsz + 4 * lane);
        pxB0 = *(const float4*)(pr0 + 2 * (size_t)Dsz + 4 * lane);
        pxA1 = *(const float4*)(pr1 + Dsz + 4 * lane);
        pxB1 = *(const float4*)(pr1 + 2 * (size_t)Dsz + 4 * lane);
    } else if (wv <= 2) {                 // lstm1: k=96, cols c0,c1 per lane
        const int p = tid - 64, u = p >> 1, odd = p & 1;
        const int c0 = odd ? 128 + u : u, c1 = c0 + 64;
#pragma unroll
        for (int j = 0; j < 48; ++j)
            wreg[j] = packh(w1g[(2 * j) * 256 + c0], w1g[(2 * j + 1) * 256 + c0]);
#pragma unroll
        for (int j = 0; j < 48; ++j)
            wreg[48 + j] = packh(w1g[(2 * j) * 256 + c1], w1g[(2 * j + 1) * 256 + c1]);
        bz0 = b1g[c0]; bz1 = b1g[c1];
    } else if (wv <= 4) {                 // lstm2: k=128
        const int p = tid - 192, u = p >> 1, odd = p & 1;
        const int c0 = odd ? 128 + u : u, c1 = c0 + 64;
#pragma unroll
        for (int j = 0; j < 64; ++j)
            wreg[j] = packh(w2g[(2 * j) * 256 + c0], w2g[(2 * j + 1) * 256 + c0]);
#pragma unroll
        for (int j = 0; j < 64; ++j)
            wreg[64 + j] = packh(w2g[(2 * j) * 256 + c1], w2g[(2 * j + 1) * 256 + c1]);
        bz0 = b2g[c0]; bz1 = b2g[c1];
    } else if (wv == 5) {                 // gx: h2 @ gru_wi (+ all gru biases)
#pragma unroll
        for (int j = 0; j < 32; ++j) {
            wreg[j]      = packh(gwi[(2 * j) * 192 + lane],       gwi[(2 * j + 1) * 192 + lane]);
            wreg[32 + j] = packh(gwi[(2 * j) * 192 + 64 + lane],  gwi[(2 * j + 1) * 192 + 64 + lane]);
            wreg[64 + j] = packh(gwi[(2 * j) * 192 + 128 + lane], gwi[(2 * j + 1) * 192 + 128 + lane]);
        }
        bz0 = gb[lane]; bz1 = gb[64 + lane]; bz2 = gb[128 + lane];
    } else {                              // gru recurrent: h3 @ gru_wh
#pragma unroll
        for (int j = 0; j < 32; ++j) {
            wreg[j]      = packh(gwh[(2 * j) * 192 + lane],       gwh[(2 * j + 1) * 192 + lane]);
            wreg[32 + j] = packh(gwh[(2 * j) * 192 + 64 + lane],  gwh[(2 * j + 1) * 192 + 64 + lane]);
            wreg[64 + j] = packh(gwh[(2 * j) * 192 + 128 + lane], gwh[(2 * j + 1) * 192 + 128 + lane]);
        }
    }

    for (int i = tid; i < 2 * 2 * 32;  i += 448) ((_Float16*)h0b)[i] = (_Float16)0.f;
    for (int i = tid; i < 2 * 2 * 64;  i += 448) ((_Float16*)h1b)[i] = (_Float16)0.f;
    for (int i = tid; i < 2 * 2 * 64;  i += 448) ((_Float16*)h2b)[i] = (_Float16)0.f;
    for (int i = tid; i < 2 * 2 * 192; i += 448) ((_Float16*)gxb)[i] = (_Float16)0.f;
    for (int i = tid; i < 2 * 64; i += 448) { ((_Float16*)h3s)[i] = (_Float16)0.f; ((_Float16*)rh3s)[i] = (_Float16)0.f; }
    __syncthreads();

    // ---------------- pipelined recurrence ----------------
    for (int n = 0; n < NCYC; ++n) {
        const int wb = n & 1, rb = wb ^ 1;

        if (wv == 0) {
            if (n + 1 < Tsz) {
                uint32_t* x0 = (uint32_t*)xb[wb][0];
                uint32_t* x1 = (uint32_t*)xb[wb][1];
                x0[2 * lane] = packh(pxA0.x, pxA0.y); x0[2 * lane + 1] = packh(pxA0.z, pxA0.w);
                x1[2 * lane] = packh(pxA1.x, pxA1.y); x1[2 * lane + 1] = packh(pxA1.z, pxA1.w);
            }
            pxA0 = pxB0; pxA1 = pxB1;
            if (n + 3 < Tsz) {
                pxB0 = *(const float4*)(pr0 + (size_t)(n + 3) * Dsz + 4 * lane);
                pxB1 = *(const float4*)(pr1 + (size_t)(n + 3) * Dsz + 4 * lane);
            }
            if (n < Tsz) {
                const int c = lane & 31, s = lane >> 5;
#pragma unroll
                for (int r = 0; r < 2; ++r) {
                    const uint4* xq = ((const uint4*)xb[rb][r]) + 16 * s;
                    const uint4* hq = ((const uint4*)h0b[rb][r]) + 2 * s;
                    float a0 = 0.f, a1 = 0.f;
#pragma unroll
                    for (int q = 0; q < 16; q += 2) {
                        uint4 v0 = xq[q], v1 = xq[q + 1];
                        D4(a0, &wreg[4 * q], v0);
                        D4(a1, &wreg[4 * q + 4], v1);
                    }
                    {
                        uint4 v0 = hq[0], v1 = hq[1];
                        D4(a0, &wreg[64], v0);
                        D4(a1, &wreg[68], v1);
                    }
                    float acc = a0 + a1;
                    acc += __shfl_xor(acc, 32);
                    if (s == 0) h0b[wb][r][c] = (_Float16)fmaxf(acc + bz0, 0.f);
                }
            }
        } else if (wv <= 2) {
            const int t = n - 1;
            if (0 <= t && t < Tsz) {
                const int p = tid - 64, u = p >> 1, odd = p & 1;
#pragma unroll
                for (int r = 0; r < 2; ++r) {
                    const uint4* aq = (const uint4*)h0b[rb][r];   // k 0..31
                    const uint4* bq = (const uint4*)h1b[rb][r];   // k 32..95
                    float a0 = bz0, a1 = bz1, x0 = 0.f, x1 = 0.f;
#pragma unroll
                    for (int q = 0; q < 4; ++q) {
                        uint4 v = aq[q];
                        D4X(a0, x0, &wreg[4 * q], v);
                        D4X(a1, x1, &wreg[48 + 4 * q], v);
                    }
#pragma unroll
                    for (int q = 0; q < 8; ++q) {
                        uint4 v = bq[q];
                        D4X(a0, x0, &wreg[16 + 4 * q], v);
                        D4X(a1, x1, &wreg[64 + 4 * q], v);
                    }
                    float g0 = a0 + x0, g1 = a1 + x1;
                    float send = 0.f, fq = 0.f, op = 0.f;
                    if (!odd) send = fsig(g0) * ftanh(g1);        // sig(i)*tanh(g)
                    else { fq = fsig(g0 + 1.f); op = fsig(g1); }  // sig(f+1), sig(o)
                    float prx = __shfl_xor(send, 1);
                    if (odd) {
                        float cs = r ? st1 : st0;
                        cs = fq * cs + prx;
                        if (r) st1 = cs; else st0 = cs;
                        h1b[wb][r][u] = (_Float16)(op * ftanh(cs));
                    }
                }
            }
        } else if (wv <= 4) {
            const int t = n - 2;
            if (0 <= t && t < Tsz) {
                const int p = tid - 192, u = p >> 1, odd = p & 1;
#pragma unroll
                for (int r = 0; r < 2; ++r) {
                    const uint4* aq = (const uint4*)h1b[rb][r];   // k 0..63
                    const uint4* bq = (const uint4*)h2b[rb][r];   // k 64..127
                    float a0 = bz0, a1 = bz1, x0 = 0.f, x1 = 0.f;
#pragma unroll
                    for (int q = 0; q < 8; ++q) {
                        uint4 v = aq[q];
                        D4X(a0, x0, &wreg[4 * q], v);
                        D4X(a1, x1, &wreg[64 + 4 * q], v);
                    }
#pragma unroll
                    for (int q = 0; q < 8; ++q) {
                        uint4 v = bq[q];
                        D4X(a0, x0, &wreg[32 + 4 * q], v);
                        D4X(a1, x1, &wreg[96 + 4 * q], v);
                    }
                    float g0 = a0 + x0, g1 = a1 + x1;
                    float send = 0.f, fq = 0.f, op = 0.f;
                    if (!odd) send = fsig(g0) * ftanh(g1);
                    else { fq = fsig(g0 + 1.f); op = fsig(g1); }
                    float prx = __shfl_xor(send, 1);
                    if (odd) {
                        float cs = r ? st1 : st0;
                        cs = fq * cs + prx;
                        if (r) st1 = cs; else st0 = cs;
                        h2b[wb][r][u] = (_Float16)(op * ftanh(cs));
                    }
                }
            }
        } else if (wv == 5) {
            const int t = n - 3;
            if (0 <= t && t < Tsz) {
#pragma unroll
                for (int r = 0; r < 2; ++r) {
                    const uint4* hq = (const uint4*)h2b[rb][r];
                    float az = bz0, ar = bz1, aa = bz2;
#pragma unroll
                    for (int q = 0; q < 8; ++q) {
                        uint4 v = hq[q];
                        D4(az, &wreg[4 * q], v);
                        D4(ar, &wreg[32 + 4 * q], v);
                        D4(aa, &wreg[64 + 4 * q], v);
                    }
                    gxb[wb][r][lane]       = (_Float16)az;
                    gxb[wb][r][64 + lane]  = (_Float16)ar;
                    gxb[wb][r][128 + lane] = (_Float16)aa;
                }
            }
        } else {
            const int t = n - 4;
            if (0 <= t && t < Tsz) {
                float z0, z1, ga0, ga1;
                {   // row 0 z/r
                    const uint4* hq = (const uint4*)h3s[0];
                    float az = (float)gxb[rb][0][lane], ar = (float)gxb[rb][0][64 + lane];
#pragma unroll
                    for (int q = 0; q < 8; ++q) {
                        uint4 v = hq[q];
                        D4(az, &wreg[4 * q], v);
                        D4(ar, &wreg[32 + 4 * q], v);
                    }
                    z0 = fsig(az);
                    rh3s[0][lane] = (_Float16)(fsig(ar) * st0);
                    ga0 = (float)gxb[rb][0][128 + lane];
                }
                {   // row 1 z/r
                    const uint4* hq = (const uint4*)h3s[1];
                    float az = (float)gxb[rb][1][lane], ar = (float)gxb[rb][1][64 + lane];
#pragma unroll
                    for (int q = 0; q < 8; ++q) {
                        uint4 v = hq[q];
                        D4(az, &wreg[4 * q], v);
                        D4(ar, &wreg[32 + 4 * q], v);
                    }
                    z1 = fsig(az);
                    rh3s[1][lane] = (_Float16)(fsig(ar) * st1);
                    ga1 = (float)gxb[rb][1][128 + lane];
                }
                asm volatile("s_waitcnt lgkmcnt(0)" ::: "memory");   // wave-sync LDS
                {   // row 0 a + update
                    const uint4* rq = (const uint4*)rh3s[0];
                    float aa = ga0, ab = 0.f;
#pragma unroll
                    for (int q = 0; q < 8; ++q) {
                        uint4 v = rq[q];
                        if (q & 1) { D4(ab, &wreg[64 + 4 * q], v); }
                        else       { D4(aa, &wreg[64 + 4 * q], v); }
                    }
                    float av = ftanh(aa + ab);
                    st0 = (1.f - z0) * st0 + z0 * av;
                    h3s[0][lane] = (_Float16)st0;
                }
                {   // row 1 a + update
                    const uint4* rq = (const uint4*)rh3s[1];
                    float aa = ga1, ab = 0.f;
#pragma unroll
                    for (int q = 0; q < 8; ++q) {
                        uint4 v = rq[q];
                        if (q & 1) { D4(ab, &wreg[64 + 4 * q], v); }
                        else       { D4(aa, &wreg[64 + 4 * q], v); }
                    }
                    float av = ftanh(aa + ab);
                    st1 = (1.f - z1) * st1 + z1 * av;
                    h3s[1][lane] = (_Float16)st1;
                }
            }
        }
        __syncthreads();
    }

    // ---------------- MLP head (2 rows) ----------------
    if (wv == 6) { sHf[0][lane] = st0; sHf[1][lane] = st1; }
    __syncthreads();
    if (tid < 64) {
        const int r = tid >> 5, c = tid & 31;
        float acc = mb1[c];
#pragma unroll
        for (int k = 0; k < 64; ++k) acc = fmaf(sHf[r][k], mw1[k * 32 + c], acc);
        sT[r][c] = fmaxf(acc, 0.f);
    }
    __syncthreads();
    if (tid < 64) {
        const int r = tid >> 5, c = tid & 31;
        float acc = mb2[c];
#pragma unroll
        for (int k = 0; k < 32; ++k) acc = fmaf(sT[r][k], mw2[k * 32 + c], acc);
        sT[r][32 + c] = fmaxf(acc, 0.f);
    }
    __syncthreads();
    if (tid < 24) {
        const int r = tid / 12, c = tid - 12 * r;
        float acc = mb3[c];
#pragma unroll
        for (int k = 0; k < 32; ++k) acc = fmaf(sT[r][32 + k], mw3[k * 12 + c], acc);
        sP[r][c] = acc;
    }
    __syncthreads();
    if (tid < 2) {
        float acc = 0.f;
#pragma unroll
        for (int k = 0; k < 12; ++k) acc = fmaf(sP[tid][k], sf[k], acc);
        out[24 + r0 + tid] = acc;
    }
    if (blockIdx.x == 0 && tid < 12) {
        out[tid] = sf[tid];
        out[12 + tid] = 1.0f;
    }
}

extern "C" void kernel_launch(void* const* d_in, const int* in_sizes, int n_in,
                              void* d_out, int out_size, void* d_ws, size_t ws_size,
                              hipStream_t stream) {
    (void)in_sizes; (void)n_in; (void)d_ws; (void)ws_size; (void)out_size;
    const float* pix    = (const float*)d_in[0];
    const float* van_wi = (const float*)d_in[1];
    const float* van_bi = (const float*)d_in[2];
    const float* van_wh = (const float*)d_in[3];
    const float* van_bh = (const float*)d_in[4];
    const float* w1     = (const float*)d_in[5];
    const float* b1     = (const float*)d_in[6];
    const float* w2     = (const float*)d_in[7];
    const float* b2     = (const float*)d_in[8];
    const float* gwi    = (const float*)d_in[9];
    const float* gwh    = (const float*)d_in[10];
    const float* gb     = (const float*)d_in[11];
    const float* mw1    = (const float*)d_in[12];
    const float* mb1    = (const float*)d_in[13];
    const float* mw2    = (const float*)d_in[14];
    const float* mb2    = (const float*)d_in[15];
    const float* mw3    = (const float*)d_in[16];
    const float* mb3    = (const float*)d_in[17];
    const float* sf     = (const float*)d_in[18];
    float* out = (float*)d_out;

    rnn_pipe3<<<256, 448, 0, stream>>>(
        pix, van_wi, van_bi, van_wh, van_bh,
        w1, b1, w2, b2, gwi, gwh, gb,
        mw1, mb1, mw2, mb2, mw3, mb3, sf, out);
}